// Round 3
// baseline (1219.138 us; speedup 1.0000x reference)
//
#include <hip/hip_runtime.h>
#include <hip/hip_bf16.h>

using bf16 = __hip_bfloat16;
typedef __bf16 bf16x8 __attribute__((ext_vector_type(8)));
typedef float  f32x4  __attribute__((ext_vector_type(4)));

#define B_ 8
#define S_ 2048
#define H_ 1024
#define M_ (B_ * S_)   // 16384
#define N_ (2 * H_)    // 2048
#define K_ 1024
#define CHUNKS_ 32
#define CLEN_ 64       // 32*64 = 2048 = S_

// Load 8 consecutive K-elements and return as bf16x8 (converting if f32).
__device__ __forceinline__ bf16x8 load8(const float* p) {
  const float4 a = *(const float4*)p;
  const float4 b = *(const float4*)(p + 4);
  bf16x8 r;
  r[0] = (__bf16)a.x; r[1] = (__bf16)a.y; r[2] = (__bf16)a.z; r[3] = (__bf16)a.w;
  r[4] = (__bf16)b.x; r[5] = (__bf16)b.y; r[6] = (__bf16)b.z; r[7] = (__bf16)b.w;
  return r;
}
__device__ __forceinline__ bf16x8 load8(const bf16* p) {
  return *(const bf16x8*)p;
}

// ---------------------------------------------------------------------------
// GEMM: C[m][n] = sum_k A[m][k] * W[n][k] + bias[n]  -> bf16 C
// A: M_ x K_ (f32 for layer 0, bf16 internal for layers 1-3)
// W: N_ x K_ f32 (model weights), bias: f32.
// 128x128 tile, BK=32, 4 waves x (4x4) mfma_f32_16x16x32_bf16, manual staging.
// LDS tile: 8 groups of 16 rows, group g holds rows [16g,16g+16), laid out
// [kq(4)][row(16)][8 bf16]: staging lane ell writes 16B at g*1024 + ell*16 =
// row (ell&15), k-chunk (ell>>4)*8. Fragment ds_read_b128 at base + lane*16
// yields MFMA operand layout (m = lane&15, k = (lane>>4)*8 + j).
// ---------------------------------------------------------------------------
template <typename TA>
__global__ __launch_bounds__(256, 2)
void gemm_bias(const TA* __restrict__ A, const float* __restrict__ W,
               const float* __restrict__ bias, bf16* __restrict__ C) {
  __shared__ __align__(16) char lds[16384];  // [0,8K): A-tile, [8K,16K): W-tile
  const int tid  = threadIdx.x;
  const int lane = tid & 63;
  const int wv   = tid >> 6;   // 0..3
  const int wr   = wv >> 1;    // wave's 64-row half
  const int wc   = wv & 1;     // wave's 64-col half
  const int r15  = lane & 15;
  const int kq   = lane >> 4;  // 0..3
  const int mBase = blockIdx.y * 128;
  const int nBase = blockIdx.x * 128;

  f32x4 acc[4][4];
#pragma unroll
  for (int i = 0; i < 4; ++i)
#pragma unroll
    for (int j = 0; j < 4; ++j)
#pragma unroll
      for (int r = 0; r < 4; ++r) acc[i][j][r] = 0.0f;

  for (int k0 = 0; k0 < K_; k0 += 32) {
    // Stage next tile into registers BEFORE the barrier.
    bf16x8 sa[2], sw[2];
#pragma unroll
    for (int c = 0; c < 2; ++c) {
      const int seg = wv * 2 + c;  // 16-row group 0..7
      sa[c] = load8(A + (size_t)(mBase + seg * 16 + r15) * K_ + k0 + kq * 8);
      sw[c] = load8(W + (size_t)(nBase + seg * 16 + r15) * K_ + k0 + kq * 8);
    }
    __syncthreads();  // previous iteration's readers done
#pragma unroll
    for (int c = 0; c < 2; ++c) {
      const int seg = wv * 2 + c;
      *(bf16x8*)(lds + seg * 1024 + lane * 16) = sa[c];
      *(bf16x8*)(lds + 8192 + seg * 1024 + lane * 16) = sw[c];
    }
    __syncthreads();  // tile visible to all waves

    bf16x8 af[4], bfr[4];
#pragma unroll
    for (int i = 0; i < 4; ++i)
      af[i] = *(const bf16x8*)(lds + (wr * 4 + i) * 1024 + lane * 16);
#pragma unroll
    for (int j = 0; j < 4; ++j)
      bfr[j] = *(const bf16x8*)(lds + 8192 + (wc * 4 + j) * 1024 + lane * 16);
#pragma unroll
    for (int i = 0; i < 4; ++i)
#pragma unroll
      for (int j = 0; j < 4; ++j)
        acc[i][j] = __builtin_amdgcn_mfma_f32_16x16x32_bf16(af[i], bfr[j],
                                                            acc[i][j], 0, 0, 0);
  }

  // Epilogue. C/D layout (m89-verified): col = lane&15, row = (lane>>4)*4 + r.
#pragma unroll
  for (int j = 0; j < 4; ++j) {
    const int col = nBase + wc * 64 + j * 16 + r15;
    const float bv = bias[col];
#pragma unroll
    for (int i = 0; i < 4; ++i) {
      const int row = mBase + wr * 64 + i * 16 + kq * 4;
#pragma unroll
      for (int r = 0; r < 4; ++r)
        C[(size_t)(row + r) * N_ + col] = __float2bfloat16(acc[i][j][r] + bv);
    }
  }
}

// ---------------------------------------------------------------------------
// Scan pointwise math:  h_t = ca*h_{t-1} + cb
//   ca = 1 - z = 1/(1+exp(gate));  cb = z * g(hidden)
//   g(x) = x + 0.5 (x>=0) else sigmoid(x)
// ---------------------------------------------------------------------------
__device__ __forceinline__ float rcpf(float x) { return __builtin_amdgcn_rcpf(x); }

__device__ __forceinline__ void step_coeffs(float gate, float hidden,
                                            float& ca, float& cb) {
  const float e1 = __expf(gate);
  ca = rcpf(1.0f + e1);          // gate->+inf: rcp(inf)=0 ; ->-inf: 1
  const float z = 1.0f - ca;
  float g;
  if (hidden >= 0.0f) {
    g = hidden + 0.5f;
  } else {
    const float e2 = __expf(hidden);  // e2 in (0,1): no overflow
    g = e2 * rcpf(1.0f + e2);
  }
  cb = z * g;
}

__device__ __forceinline__ float g_of(float x) {
  if (x >= 0.0f) return x + 0.5f;
  const float e = __expf(x);
  return e * rcpf(1.0f + e);
}

// Phase A: per (channel, chunk) composed affine (A,B): h_out = A*h_in + B
__global__ __launch_bounds__(256)
void scan_chunk(const bf16* __restrict__ gh, float2* __restrict__ sAB) {
  const int tx = threadIdx.x, bx = blockIdx.x;
  const int hb = bx & 3, b = (bx >> 2) & 7, j = bx >> 5;
  const int hh = hb * 256 + tx;
  const int c = b * 1024 + hh;
  const bf16* gbase = gh + ((size_t)(b * S_ + j * CLEN_)) * N_ + hh;
  float A = 1.0f, Bc = 0.0f;
#pragma unroll 8
  for (int t = 0; t < CLEN_; ++t) {
    const float gate   = __bfloat162float(gbase[(size_t)t * N_]);
    const float hidden = __bfloat162float(gbase[(size_t)t * N_ + H_]);
    float ca, cb;
    step_coeffs(gate, hidden, ca, cb);
    A *= ca;
    Bc = ca * Bc + cb;
  }
  sAB[j * (B_ * H_) + c] = make_float2(A, Bc);
}

// Phase B: scan the 32 chunk summaries per channel; carry_in per chunk.
__global__ __launch_bounds__(256)
void scan_carry(const float2* __restrict__ sAB, const float* __restrict__ hprev,
                float* __restrict__ carry) {
  const int c = blockIdx.x * 256 + threadIdx.x;  // 0..8191
  float Hc = g_of(hprev[c]);                     // h_0 = g(h_prev)
#pragma unroll
  for (int j = 0; j < CHUNKS_; ++j) {
    carry[j * (B_ * H_) + c] = Hc;
    const float2 ab = sAB[j * (B_ * H_) + c];
    Hc = ab.x * Hc + ab.y;
  }
}

// Phase C: re-walk chunk from its carry; residual stream in f32 (in-place on
// rout is safe: per-thread element-wise read-before-write on disjoint elems).
// gout (optional): bf16 copy of the residual stream for the next layer's GEMM.
__global__ __launch_bounds__(256)
void scan_apply(const bf16* __restrict__ gh, const float* __restrict__ carry,
                const float* rin, float* rout, bf16* gout,
                float* __restrict__ finals) {
  const int tx = threadIdx.x, bx = blockIdx.x;
  const int hb = bx & 3, b = (bx >> 2) & 7, j = bx >> 5;
  const int hh = hb * 256 + tx;
  const int c = b * 1024 + hh;
  const size_t base = ((size_t)(b * S_ + j * CLEN_)) * H_ + hh;
  const bf16* gbase = gh + ((size_t)(b * S_ + j * CLEN_)) * N_ + hh;
  float h = carry[j * (B_ * H_) + c];
#pragma unroll 4
  for (int t = 0; t < CLEN_; ++t) {
    const float gate   = __bfloat162float(gbase[(size_t)t * N_]);
    const float hidden = __bfloat162float(gbase[(size_t)t * N_ + H_]);
    float ca, cb;
    step_coeffs(gate, hidden, ca, cb);
    h = ca * h + cb;
    const float r = h + rin[base + (size_t)t * H_];
    rout[base + (size_t)t * H_] = r;
    if (gout) gout[base + (size_t)t * H_] = __float2bfloat16(r);
  }
  if (j == CHUNKS_ - 1) finals[c] = h;  // pre-residual h_S
}

// ---------------------------------------------------------------------------
extern "C" void kernel_launch(void* const* d_in, const int* in_sizes, int n_in,
                              void* d_out, int out_size, void* d_ws,
                              size_t ws_size, hipStream_t stream) {
  const float* x  = (const float*)d_in[0];
  const float* h0 = (const float*)d_in[1];  // (L,B,1,H)
  const float* W0 = (const float*)d_in[2];  // (2H, D)
  const float* b0 = (const float*)d_in[3];  // (2H,)
  const float* Wl = (const float*)d_in[4];  // (L-1, 2H, H)
  const float* bl = (const float*)d_in[5];  // (L-1, 2H)
  float* out    = (float*)d_out;            // (B,S,H) residual stream, in-place
  float* finals = out + (size_t)M_ * H_;    // (L,B,1,H)

  // ws: gh 64MB + bufA 32MB + sAB 2MB + carry 1MB = 99MB
  char* ws = (char*)d_ws;
  bf16*   gh    = (bf16*)ws;                    // (M_, 2H) bf16
  bf16*   bufA  = (bf16*)(ws + (64u << 20));    // bf16 copy of residual stream
  float2* sAB   = (float2*)(ws + (96u << 20));
  float*  carry = (float*)(ws + (98u << 20));

  for (int l = 0; l < 4; ++l) {
    if (l == 0) {
      gemm_bias<float><<<dim3(16, 128), 256, 0, stream>>>(x, W0, b0, gh);
    } else {
      gemm_bias<bf16><<<dim3(16, 128), 256, 0, stream>>>(
          bufA, Wl + (size_t)(l - 1) * N_ * K_, bl + (size_t)(l - 1) * N_, gh);
    }
    scan_chunk<<<dim3(4 * 8 * CHUNKS_), 256, 0, stream>>>(gh, sAB);
    scan_carry<<<dim3(32), 256, 0, stream>>>(sAB, h0 + (size_t)l * B_ * H_, carry);
    scan_apply<<<dim3(4 * 8 * CHUNKS_), 256, 0, stream>>>(
        gh, carry, (l == 0) ? x : out, out, (l == 3) ? nullptr : bufA,
        finals + (size_t)l * B_ * H_);
  }
}

// Round 4
// 987.975 us; speedup vs baseline: 1.2340x; 1.2340x over previous
//
#include <hip/hip_runtime.h>
#include <hip/hip_bf16.h>

using bf16 = __hip_bfloat16;
typedef __bf16 bf16x8 __attribute__((ext_vector_type(8)));
typedef float  f32x4  __attribute__((ext_vector_type(4)));

#define B_ 8
#define S_ 2048
#define H_ 1024
#define M_ (B_ * S_)   // 16384
#define N_ (2 * H_)    // 2048
#define K_ 1024
#define CHUNKS_ 32
#define CLEN_ 64       // 32*64 = 2048 = S_

__device__ __forceinline__ bf16x8 load8f(const float* p) {
  const float4 a = *(const float4*)p;
  const float4 b = *(const float4*)(p + 4);
  bf16x8 r;
  r[0] = (__bf16)a.x; r[1] = (__bf16)a.y; r[2] = (__bf16)a.z; r[3] = (__bf16)a.w;
  r[4] = (__bf16)b.x; r[5] = (__bf16)b.y; r[6] = (__bf16)b.z; r[7] = (__bf16)b.w;
  return r;
}

// f32 -> bf16 bulk convert, 8 elems/thread. n must be multiple of 8.
__global__ __launch_bounds__(256)
void cvt_f32_bf16(const float* __restrict__ src, bf16* __restrict__ dst, long n) {
  const long i = ((long)blockIdx.x * 256 + threadIdx.x) * 8;
  if (i >= n) return;
  *(bf16x8*)(dst + i) = load8f(src + i);
}

// ---------------------------------------------------------------------------
// GEMM: C[m][n] = sum_k A[m][k] * Wb[n][k] + bias[n]  -> bf16 C
// m97 structure: 128x128 tile, BK=32, 4 waves x (4x4) mfma_f32_16x16x32_bf16,
// global_load_lds width=16 for A (and W when WDMA).
// LDS tile: 8 groups of 16 rows; group g = 1KB as [kq(4)][row(16)][16B].
// DMA HW scatter: lane ell -> group_base + ell*16 == row (ell&15),
// k-chunk (ell>>4); matches the per-lane global address below. Fragment
// ds_read_b128 at base + lane*16 yields MFMA operand layout
// (m = lane&15, k = (lane>>4)*8 + j). Layout verified correct in round 3.
// ---------------------------------------------------------------------------
template <bool WDMA>
__global__ __launch_bounds__(256)
void gemm_bias(const bf16* __restrict__ A, const bf16* __restrict__ Wb,
               const float* __restrict__ Wf, const float* __restrict__ bias,
               bf16* __restrict__ C) {
  __shared__ __align__(16) char lds[16384];  // [0,8K): A-tile, [8K,16K): W-tile
  const int tid  = threadIdx.x;
  const int lane = tid & 63;
  const int wv   = tid >> 6;   // 0..3
  const int wr   = wv >> 1;    // wave's 64-row half
  const int wc   = wv & 1;     // wave's 64-col half
  const int r15  = lane & 15;
  const int kq   = lane >> 4;  // 0..3
  const int mBase = blockIdx.y * 128;
  const int nBase = blockIdx.x * 128;

  f32x4 acc[4][4];
#pragma unroll
  for (int i = 0; i < 4; ++i)
#pragma unroll
    for (int j = 0; j < 4; ++j)
#pragma unroll
      for (int r = 0; r < 4; ++r) acc[i][j][r] = 0.0f;

  for (int k0 = 0; k0 < K_; k0 += 32) {
    bf16x8 sw[2];
    if constexpr (!WDMA) {
      // Prefetch W (f32) into registers before the barrier.
#pragma unroll
      for (int c = 0; c < 2; ++c) {
        const int seg = wv * 2 + c;
        sw[c] = load8f(Wf + (size_t)(nBase + seg * 16 + r15) * K_ + k0 + kq * 8);
      }
    }
    __syncthreads();  // previous iteration's LDS readers done
#pragma unroll
    for (int c = 0; c < 2; ++c) {
      const int seg = wv * 2 + c;  // 16-row group 0..7 (wave-uniform)
      const bf16* ga = A + (size_t)(mBase + seg * 16 + r15) * K_ + k0 + kq * 8;
      __builtin_amdgcn_global_load_lds(
          (const __attribute__((address_space(1))) void*)ga,
          (__attribute__((address_space(3))) void*)(lds + seg * 1024), 16, 0, 0);
      if constexpr (WDMA) {
        const bf16* gw = Wb + (size_t)(nBase + seg * 16 + r15) * K_ + k0 + kq * 8;
        __builtin_amdgcn_global_load_lds(
            (const __attribute__((address_space(1))) void*)gw,
            (__attribute__((address_space(3))) void*)(lds + 8192 + seg * 1024), 16, 0, 0);
      } else {
        *(bf16x8*)(lds + 8192 + seg * 1024 + lane * 16) = sw[c];
      }
    }
    __syncthreads();  // drains vmcnt+lgkmcnt: tile visible to all waves

    bf16x8 af[4], bfr[4];
#pragma unroll
    for (int i = 0; i < 4; ++i)
      af[i] = *(const bf16x8*)(lds + (wr * 4 + i) * 1024 + lane * 16);
#pragma unroll
    for (int j = 0; j < 4; ++j)
      bfr[j] = *(const bf16x8*)(lds + 8192 + (wc * 4 + j) * 1024 + lane * 16);
#pragma unroll
    for (int i = 0; i < 4; ++i)
#pragma unroll
      for (int j = 0; j < 4; ++j)
        acc[i][j] = __builtin_amdgcn_mfma_f32_16x16x32_bf16(af[i], bfr[j],
                                                            acc[i][j], 0, 0, 0);
  }

  // Epilogue. C/D layout: col = lane&15, row = (lane>>4)*4 + r (r3-verified).
#pragma unroll
  for (int j = 0; j < 4; ++j) {
    const int col = nBase + wc * 64 + j * 16 + r15;
    const float bv = bias[col];
#pragma unroll
    for (int i = 0; i < 4; ++i) {
      const int row = mBase + wr * 64 + i * 16 + kq * 4;
#pragma unroll
      for (int r = 0; r < 4; ++r)
        C[(size_t)(row + r) * N_ + col] = __float2bfloat16(acc[i][j][r] + bv);
    }
  }
}

// ---------------------------------------------------------------------------
// Scan pointwise math:  h_t = ca*h_{t-1} + cb
//   ca = 1 - z = 1/(1+exp(gate));  cb = z * g(hidden)
//   g(x) = x + 0.5 (x>=0) else sigmoid(x)
// ---------------------------------------------------------------------------
__device__ __forceinline__ float rcpf(float x) { return __builtin_amdgcn_rcpf(x); }

__device__ __forceinline__ void step_coeffs(float gate, float hidden,
                                            float& ca, float& cb) {
  const float e1 = __expf(gate);
  ca = rcpf(1.0f + e1);          // gate->+inf: rcp(inf)=0 ; ->-inf: 1
  const float z = 1.0f - ca;
  float g;
  if (hidden >= 0.0f) {
    g = hidden + 0.5f;
  } else {
    const float e2 = __expf(hidden);  // e2 in (0,1): no overflow
    g = e2 * rcpf(1.0f + e2);
  }
  cb = z * g;
}

__device__ __forceinline__ float g_of(float x) {
  if (x >= 0.0f) return x + 0.5f;
  const float e = __expf(x);
  return e * rcpf(1.0f + e);
}

// Phase A: per (channel, chunk) composed affine (A,B): h_out = A*h_in + B
__global__ __launch_bounds__(256)
void scan_chunk(const bf16* __restrict__ gh, float2* __restrict__ sAB) {
  const int tx = threadIdx.x, bx = blockIdx.x;
  const int hb = bx & 3, b = (bx >> 2) & 7, j = bx >> 5;
  const int hh = hb * 256 + tx;
  const int c = b * 1024 + hh;
  const bf16* gbase = gh + ((size_t)(b * S_ + j * CLEN_)) * N_ + hh;
  float A = 1.0f, Bc = 0.0f;
#pragma unroll 8
  for (int t = 0; t < CLEN_; ++t) {
    const float gate   = __bfloat162float(gbase[(size_t)t * N_]);
    const float hidden = __bfloat162float(gbase[(size_t)t * N_ + H_]);
    float ca, cb;
    step_coeffs(gate, hidden, ca, cb);
    A *= ca;
    Bc = ca * Bc + cb;
  }
  sAB[j * (B_ * H_) + c] = make_float2(A, Bc);
}

// Phase B: scan the 32 chunk summaries per channel; carry_in per chunk.
__global__ __launch_bounds__(256)
void scan_carry(const float2* __restrict__ sAB, const float* __restrict__ hprev,
                float* __restrict__ carry) {
  const int c = blockIdx.x * 256 + threadIdx.x;  // 0..8191
  float Hc = g_of(hprev[c]);                     // h_0 = g(h_prev)
#pragma unroll
  for (int j = 0; j < CHUNKS_; ++j) {
    carry[j * (B_ * H_) + c] = Hc;
    const float2 ab = sAB[j * (B_ * H_) + c];
    Hc = ab.x * Hc + ab.y;
  }
}

// Phase C: re-walk chunk from its carry; residual stream in f32 (in-place on
// rout is race-free: element-wise read-before-write on disjoint elements).
// gout (optional): bf16 copy of the residual stream for the next layer GEMM.
__global__ __launch_bounds__(256)
void scan_apply(const bf16* __restrict__ gh, const float* __restrict__ carry,
                const float* rin, float* rout, bf16* gout,
                float* __restrict__ finals) {
  const int tx = threadIdx.x, bx = blockIdx.x;
  const int hb = bx & 3, b = (bx >> 2) & 7, j = bx >> 5;
  const int hh = hb * 256 + tx;
  const int c = b * 1024 + hh;
  const size_t base = ((size_t)(b * S_ + j * CLEN_)) * H_ + hh;
  const bf16* gbase = gh + ((size_t)(b * S_ + j * CLEN_)) * N_ + hh;
  float h = carry[j * (B_ * H_) + c];
#pragma unroll 4
  for (int t = 0; t < CLEN_; ++t) {
    const float gate   = __bfloat162float(gbase[(size_t)t * N_]);
    const float hidden = __bfloat162float(gbase[(size_t)t * N_ + H_]);
    float ca, cb;
    step_coeffs(gate, hidden, ca, cb);
    h = ca * h + cb;
    const float r = h + rin[base + (size_t)t * H_];
    rout[base + (size_t)t * H_] = r;
    if (gout) gout[base + (size_t)t * H_] = __float2bfloat16(r);
  }
  if (j == CHUNKS_ - 1) finals[c] = h;  // pre-residual h_S
}

// ---------------------------------------------------------------------------
extern "C" void kernel_launch(void* const* d_in, const int* in_sizes, int n_in,
                              void* d_out, int out_size, void* d_ws,
                              size_t ws_size, hipStream_t stream) {
  const float* x  = (const float*)d_in[0];
  const float* h0 = (const float*)d_in[1];  // (L,B,1,H)
  const float* W0 = (const float*)d_in[2];  // (2H, D)
  const float* b0 = (const float*)d_in[3];  // (2H,)
  const float* Wl = (const float*)d_in[4];  // (L-1, 2H, H)
  const float* bl = (const float*)d_in[5];  // (L-1, 2H)
  float* out    = (float*)d_out;            // (B,S,H) residual stream, in-place
  float* finals = out + (size_t)M_ * H_;    // (L,B,1,H)

  char* ws = (char*)d_ws;
  bf16* gh   = (bf16*)ws;                   // 64 MB: (M_, 2H)
  bf16* bufA = (bf16*)(ws + (64u << 20));   // 32 MB: bf16 A for current layer

  const bool wide = ws_size >= ((size_t)115 << 20);
  bf16*   wb    = wide ? (bf16*)(ws + (96u << 20)) : nullptr;       // 16 MB
  float2* sAB   = (float2*)(ws + ((wide ? 112u : 96u) << 20));      // 2 MB
  float*  carry = (float*)(ws + ((wide ? 114u : 98u) << 20));       // 1 MB

  // x -> bf16 into bufA (layer-0 A). 16M elems.
  cvt_f32_bf16<<<dim3(M_ * K_ / 8 / 256), 256, 0, stream>>>(x, bufA, (long)M_ * K_);
  if (wide) {  // all weights -> bf16 once: [W0 | Wl] = 4 x (2048x1024)
    cvt_f32_bf16<<<dim3(N_ * K_ / 8 / 256), 256, 0, stream>>>(W0, wb, (long)N_ * K_);
    cvt_f32_bf16<<<dim3(3 * N_ * K_ / 8 / 256), 256, 0, stream>>>(
        Wl, wb + (size_t)N_ * K_, (long)3 * N_ * K_);
  }

  for (int l = 0; l < 4; ++l) {
    const float* Wf = (l == 0) ? W0 : Wl + (size_t)(l - 1) * N_ * K_;
    const float* bi = (l == 0) ? b0 : bl + (size_t)(l - 1) * N_;
    if (wide) {
      gemm_bias<true><<<dim3(16, 128), 256, 0, stream>>>(
          bufA, wb + (size_t)l * N_ * K_, nullptr, bi, gh);
    } else {
      gemm_bias<false><<<dim3(16, 128), 256, 0, stream>>>(
          bufA, nullptr, Wf, bi, gh);
    }
    scan_chunk<<<dim3(4 * 8 * CHUNKS_), 256, 0, stream>>>(gh, sAB);
    scan_carry<<<dim3(32), 256, 0, stream>>>(sAB, h0 + (size_t)l * B_ * H_, carry);
    scan_apply<<<dim3(4 * 8 * CHUNKS_), 256, 0, stream>>>(
        gh, carry, (l == 0) ? x : out, out, (l == 3) ? nullptr : bufA,
        finals + (size_t)l * B_ * H_);
  }
}